// Round 5
// baseline (332.939 us; speedup 1.0000x reference)
//
#include <hip/hip_runtime.h>
#include <hip/hip_bf16.h>

#define T_LEN 1024
#define NH    16
#define CH    64
#define LSTR  64        // LDS bf16 row stride in shorts: 128 B, swizzled (no pad)
#define OSTR  68        // epilogue fp32 row stride in floats

typedef __attribute__((ext_vector_type(8))) short short8;
typedef __attribute__((ext_vector_type(4))) float floatx4;
typedef unsigned long long u64;

__device__ __forceinline__ short f2bf(float x) {
    __hip_bfloat16 b = __float2bfloat16(x);   // RNE
    return *(short*)&b;
}
// XOR block-swizzle for stride-64-short (128 B) rows.
__device__ __forceinline__ int fsw(int row) {
    return (((row & 7) ^ ((row >> 3) & 7)) << 3);
}

// ---- mask bit-pack: (8,1024,1024) int32 -> (8,1024,16) u64 via wave ballot ----
__global__ __launch_bounds__(256)
void pack_mask_kernel(const int* __restrict__ mask, u64* __restrict__ pm)
{
    const int NW = 8 * T_LEN * (T_LEN / 64);   // 131072 words
    const int lane = threadIdx.x & 63;
    const int gw = (int)((blockIdx.x * blockDim.x + threadIdx.x) >> 6);
    const int nw = (int)((gridDim.x * blockDim.x) >> 6);
    for (int w0 = gw; w0 < NW; w0 += 4 * nw) {
        int v[4];
        #pragma unroll
        for (int i = 0; i < 4; ++i) {
            const int w = w0 + i * nw;
            v[i] = (w < NW) ? mask[(size_t)w * 64 + lane] : 0;
        }
        #pragma unroll
        for (int i = 0; i < 4; ++i) {
            const int w = w0 + i * nw;
            const u64 bb = __ballot(v[i] != 0);
            if (lane == 0 && w < NW) pm[w] = bb;
        }
    }
}

// One block = 4 waves = 256 threads: one (head-batch, 64-row Q tile).
// OCCUPANCY-FIRST: 24 KB LDS (Q/P overlay 8K + single-buffered K 8K + V 8K)
// -> up to 6 blocks/CU; VGPR-capped ~5 -> ~20 waves/CU in 5 INDEPENDENT
// 4-wave barrier groups (vs 2x8-wave lockstep groups before). K/V global
// loads for tile i+1 issue at compute-start of tile i (full compute phase
// covers HBM latency); only cvt+LDS-write sits between the two barriers.
// Packed-bit mask, pre-scaled Q (0.125*log2e), bias*log2e as MFMA C-init,
// exp2 softmax, ones-MFMA row sums.
// launch_bounds 2nd arg = workgroups/CU: cap = 2048*4/(threads*k/64).
// (256,4) -> 128-VGPR cap (est usage ~100, no spill; r2's spill tripwire:
// FETCH_SIZE ballooning).
template<bool PM>
__global__ __launch_bounds__(256, 4)
void qkv_attn_kernel(const float* __restrict__ qkv,
                     const int* __restrict__ mask,
                     const u64* __restrict__ pm,
                     const float* __restrict__ qk_bias,
                     float* __restrict__ out)
{
    // rows of LSTR shorts: Q/P overlay [64] | K [64] | V [64]
    __shared__ __align__(16) char smem[(64 + 2 * 64) * LSTR * 2];  // 24576 B
    short* Qs = (short*)smem;             // [t][c] swizzled; P overlays per-wave rows
    short* Ks = Qs + 64 * LSTR;           // [s][c] swizzled, single-buffered
    short* Vs = Ks + 64 * LSTR;           // [c][s] swizzled, single-buffered
    float* Os = (float*)smem;             // epilogue reuse: 64 x OSTR fp32 = 17408 B

    const int tid  = threadIdx.x;
    const int wave = tid >> 6;            // 0..3
    const int lane = tid & 63;
    const int quad = lane >> 4;
    const int l16  = lane & 15;

    const int bh    = blockIdx.x;   // 0..127: consecutive bh -> XCD round-robin
    const int qtile = blockIdx.y;   // 0..15: stride-128 ids keep a bh on ONE XCD
    const int b     = bh >> 4;
    const int h     = bh & 15;
    const int t0    = qtile * 64;

    const size_t qbase = ((size_t)b * (3 * NH * CH) + (size_t)h * (3 * CH)) * T_LEN;
    const float* kp = qkv + qbase + (size_t)CH * T_LEN;
    const float* vp = qkv + qbase + (size_t)(2 * CH) * T_LEN;

    const float b_l2e  = qk_bias[0] * 1.44269504088896f;  // exp(x)=exp2(x*log2e)
    const float qscale = 0.125f * 1.44269504088896f;      // folded into Q staging

    const int c64 = tid >> 2;          // 0..63 channel row
    const int seg = (tid & 3) * 16;    // 16-element segment per thread

    const float* kpr = kp + (size_t)c64 * T_LEN;
    const float* vpr = vp + (size_t)c64 * T_LEN;

    const int trow = t0 + wave * 16 + quad * 4;
    const u64* pmb = PM ? pm + ((size_t)(h & 7) * T_LEN + trow) * (T_LEN / 64) : nullptr;
    const int* mbase = mask + (size_t)(h & 7) * T_LEN * T_LEN;

    // ---- issue prefetch of K/V tile 0 + mask words it=0 ----
    float4 ka[4], va[4];
    #pragma unroll
    for (int j = 0; j < 4; ++j) {
        ka[j] = *(const float4*)(kpr + seg + 4 * j);
        va[j] = *(const float4*)(vpr + seg + 4 * j);
    }
    u64 m[4];
    if (PM) {
        #pragma unroll
        for (int r = 0; r < 4; ++r) m[r] = pmb[r * (T_LEN / 64)];
    }

    // ---- stage Q transposed + swizzled + PRE-SCALED (fp32 -> bf16) ----
    {
        const float* src = qkv + qbase + (size_t)c64 * T_LEN + t0 + seg;
        #pragma unroll
        for (int k = 0; k < 4; ++k) {
            float4 f = *(const float4*)(src + 4 * k);
            const int t = seg + 4 * k;
            Qs[(t + 0) * LSTR + (c64 ^ fsw(t + 0))] = f2bf(f.x * qscale);
            Qs[(t + 1) * LSTR + (c64 ^ fsw(t + 1))] = f2bf(f.y * qscale);
            Qs[(t + 2) * LSTR + (c64 ^ fsw(t + 2))] = f2bf(f.z * qscale);
            Qs[(t + 3) * LSTR + (c64 ^ fsw(t + 3))] = f2bf(f.w * qscale);
        }
    }

    // ---- stage K/V tile 0 ----
    {
        #pragma unroll
        for (int j = 0; j < 4; ++j) {
            const float4 f = ka[j];
            const int s = seg + 4 * j;
            Ks[(s + 0) * LSTR + (c64 ^ fsw(s + 0))] = f2bf(f.x);
            Ks[(s + 1) * LSTR + (c64 ^ fsw(s + 1))] = f2bf(f.y);
            Ks[(s + 2) * LSTR + (c64 ^ fsw(s + 2))] = f2bf(f.z);
            Ks[(s + 3) * LSTR + (c64 ^ fsw(s + 3))] = f2bf(f.w);
        }
        const short8 vb0 = { f2bf(va[0].x), f2bf(va[0].y), f2bf(va[0].z), f2bf(va[0].w),
                             f2bf(va[1].x), f2bf(va[1].y), f2bf(va[1].z), f2bf(va[1].w) };
        const short8 vb1 = { f2bf(va[2].x), f2bf(va[2].y), f2bf(va[2].z), f2bf(va[2].w),
                             f2bf(va[3].x), f2bf(va[3].y), f2bf(va[3].z), f2bf(va[3].w) };
        *(short8*)&Vs[c64 * LSTR + ((seg)     ^ fsw(c64))] = vb0;
        *(short8*)&Vs[c64 * LSTR + ((seg + 8) ^ fsw(c64))] = vb1;
    }
    __syncthreads();

    // ---- loop-invariant Q fragments (before any P write to same rows) ----
    const int qrow = wave * 16 + l16;
    const short8 aq0 = *(const short8*)&Qs[qrow * LSTR + ((quad * 8)      ^ fsw(qrow))];
    const short8 aq1 = *(const short8*)&Qs[qrow * LSTR + ((quad * 8 + 32) ^ fsw(qrow))];

    const short one_bf = (short)0x3F80;
    const short8 ones8 = (short8){one_bf, one_bf, one_bf, one_bf,
                                  one_bf, one_bf, one_bf, one_bf};

    floatx4 o[4], ol;
    #pragma unroll
    for (int i = 0; i < 4; ++i) o[i] = (floatx4){0.f, 0.f, 0.f, 0.f};
    ol = (floatx4){0.f, 0.f, 0.f, 0.f};

    // P overlays this wave's own 16 Q rows (wave-private; Q already consumed)
    short* Pw = Qs + wave * 16 * LSTR;
    int fpw[4];
    #pragma unroll
    for (int r = 0; r < 4; ++r) fpw[r] = fsw(wave * 16 + quad * 4 + r);
    const int apof0 = (quad * 8)      ^ fsw(wave * 16 + l16);
    const int apof1 = (quad * 8 + 32) ^ fsw(wave * 16 + l16);

    for (int it = 0; it < 16; ++it) {
        const int s0 = it * 64;

        // issue next-tile K/V global loads (full compute phase covers latency)
        if (it < 15) {
            #pragma unroll
            for (int j = 0; j < 4; ++j) {
                ka[j] = *(const float4*)(kpr + s0 + 64 + seg + 4 * j);
                va[j] = *(const float4*)(vpr + s0 + 64 + seg + 4 * j);
            }
        }

        // ---- S = QK^T (scale/bias pre-folded) -> P = exp2(acc) masked ----
        #pragma unroll
        for (int sub = 0; sub < 4; ++sub) {
            const int srow = sub * 16 + l16;
            const int fk   = fsw(srow);
            const short8 bk0 = *(const short8*)&Ks[srow * LSTR + ((quad * 8)      ^ fk)];
            const short8 bk1 = *(const short8*)&Ks[srow * LSTR + ((quad * 8 + 32) ^ fk)];
            floatx4 acc = (floatx4){b_l2e, b_l2e, b_l2e, b_l2e};
            acc = __builtin_amdgcn_mfma_f32_16x16x32_bf16(aq0, bk0, acc, 0, 0, 0);
            acc = __builtin_amdgcn_mfma_f32_16x16x32_bf16(aq1, bk1, acc, 0, 0, 0);
            const int bit = sub * 16 + l16;
            #pragma unroll
            for (int r = 0; r < 4; ++r) {
                bool keep;
                if (PM) keep = ((m[r] >> bit) & 1ULL) != 0;
                else    keep = mbase[(size_t)(trow + r) * T_LEN + s0 + bit] != 0;
                const float e = __builtin_amdgcn_exp2f(acc[r]);
                Pw[(quad * 4 + r) * LSTR + ((sub * 16 + l16) ^ fpw[r])] =
                    f2bf(keep ? e : 0.f);
            }
        }

        // reload mask words for next iter (L2-resident; hidden under PV)
        if (PM && it < 15) {
            #pragma unroll
            for (int r = 0; r < 4; ++r) m[r] = pmb[r * (T_LEN / 64) + it + 1];
        }

        // ---- per-wave P fragments (wave-private rows, no barrier) ----
        const short8 ap0 = *(const short8*)&Pw[l16 * LSTR + apof0];
        const short8 ap1 = *(const short8*)&Pw[l16 * LSTR + apof1];

        // ---- O += P V ; l += P . 1 ----
        __builtin_amdgcn_s_setprio(1);
        #pragma unroll
        for (int csub = 0; csub < 4; ++csub) {
            const int vrow = csub * 16 + l16;
            const int fv   = fsw(vrow);
            const short8 bv0 = *(const short8*)&Vs[vrow * LSTR + ((quad * 8)      ^ fv)];
            const short8 bv1 = *(const short8*)&Vs[vrow * LSTR + ((quad * 8 + 32) ^ fv)];
            o[csub] = __builtin_amdgcn_mfma_f32_16x16x32_bf16(ap0, bv0, o[csub], 0, 0, 0);
            o[csub] = __builtin_amdgcn_mfma_f32_16x16x32_bf16(ap1, bv1, o[csub], 0, 0, 0);
        }
        ol = __builtin_amdgcn_mfma_f32_16x16x32_bf16(ap0, ones8, ol, 0, 0, 0);
        ol = __builtin_amdgcn_mfma_f32_16x16x32_bf16(ap1, ones8, ol, 0, 0, 0);
        __builtin_amdgcn_s_setprio(0);

        // ---- single-buffer refill: cvt in regs, then write between barriers ----
        if (it < 15) {
            short kb[16];
            #pragma unroll
            for (int j = 0; j < 4; ++j) {
                kb[4 * j + 0] = f2bf(ka[j].x);
                kb[4 * j + 1] = f2bf(ka[j].y);
                kb[4 * j + 2] = f2bf(ka[j].z);
                kb[4 * j + 3] = f2bf(ka[j].w);
            }
            const short8 vb0 = { f2bf(va[0].x), f2bf(va[0].y), f2bf(va[0].z), f2bf(va[0].w),
                                 f2bf(va[1].x), f2bf(va[1].y), f2bf(va[1].z), f2bf(va[1].w) };
            const short8 vb1 = { f2bf(va[2].x), f2bf(va[2].y), f2bf(va[2].z), f2bf(va[2].w),
                                 f2bf(va[3].x), f2bf(va[3].y), f2bf(va[3].z), f2bf(va[3].w) };
            __syncthreads();   // all waves done reading Ks/Vs
            #pragma unroll
            for (int j = 0; j < 16; ++j)
                Ks[(seg + j) * LSTR + (c64 ^ fsw(seg + j))] = kb[j];
            *(short8*)&Vs[c64 * LSTR + ((seg)     ^ fsw(c64))] = vb0;
            *(short8*)&Vs[c64 * LSTR + ((seg + 8) ^ fsw(c64))] = vb1;
            __syncthreads();   // staged tile visible
        }
    }

    // ---- epilogue: normalize, restage fp32 via LDS for coalesced [c][t] stores ----
    __syncthreads();   // all compute done before Os overwrites Qs/Ks
    float inv[4];
    #pragma unroll
    for (int r = 0; r < 4; ++r) inv[r] = (ol[r] > 0.f) ? 1.f / ol[r] : 0.f;
    const int osw = wave << 3;                     // == ((row>>4)<<3)
    #pragma unroll
    for (int csub = 0; csub < 4; ++csub)
        #pragma unroll
        for (int r = 0; r < 4; ++r)
            Os[(wave * 16 + quad * 4 + r) * OSTR + ((csub * 16 + l16) ^ osw)] =
                o[csub][r] * inv[r];
    __syncthreads();
    {
        const int cg = c64 ^ ((tid & 3) << 3);     // reader t>>4 = tid&3
        float* dst = out + ((size_t)b * (NH * CH) + (size_t)h * CH + c64) * T_LEN
                   + t0 + seg;
        #pragma unroll
        for (int k = 0; k < 4; ++k) {
            const int t = seg + 4 * k;
            float4 f;
            f.x = Os[(t + 0) * OSTR + cg];
            f.y = Os[(t + 1) * OSTR + cg];
            f.z = Os[(t + 2) * OSTR + cg];
            f.w = Os[(t + 3) * OSTR + cg];
            *(float4*)(dst + 4 * k) = f;
        }
    }
}

extern "C" void kernel_launch(void* const* d_in, const int* in_sizes, int n_in,
                              void* d_out, int out_size, void* d_ws, size_t ws_size,
                              hipStream_t stream) {
    const float* qkv     = (const float*)d_in[0];
    const int*   mask    = (const int*)d_in[1];
    const float* qk_bias = (const float*)d_in[2];
    float*       out     = (float*)d_out;

    const size_t pm_bytes = (size_t)8 * T_LEN * (T_LEN / 64) * sizeof(u64);  // 1 MiB
    u64* pm = nullptr;
    if (d_ws && ws_size >= pm_bytes) {
        pm = (u64*)d_ws;
        pack_mask_kernel<<<2048, 256, 0, stream>>>(mask, pm);
    }

    dim3 grid(8 * NH, T_LEN / 64);  // (head-batches, q-tiles) = (128, 16)
    if (pm) qkv_attn_kernel<true ><<<grid, 256, 0, stream>>>(qkv, mask, pm, qk_bias, out);
    else    qkv_attn_kernel<false><<<grid, 256, 0, stream>>>(qkv, mask, nullptr, qk_bias, out);
}

// Round 6
// 242.009 us; speedup vs baseline: 1.3757x; 1.3757x over previous
//
#include <hip/hip_runtime.h>
#include <hip/hip_bf16.h>

#define T_LEN 1024
#define NH    16
#define CH    64
#define LSTR  64        // LDS bf16 row stride in shorts: 128 B, swizzled (no pad)
#define OSTR  68        // epilogue fp32 row stride in floats

typedef __attribute__((ext_vector_type(8))) short short8;
typedef __attribute__((ext_vector_type(4))) float floatx4;
typedef unsigned long long u64;

__device__ __forceinline__ short f2bf(float x) {
    __hip_bfloat16 b = __float2bfloat16(x);   // RNE
    return *(short*)&b;
}
// XOR block-swizzle for stride-64-short (128 B) rows.
__device__ __forceinline__ int fsw(int row) {
    return (((row & 7) ^ ((row >> 3) & 7)) << 3);
}
// K-row permutation: store original s at physical row p so that after the
// 4 sub-tile QK^T MFMAs, lane (q,l16) holds exactly s in {8q..8q+3 (sub0),
// 8q+4..7 (sub1), 32+8q+0..3 (sub2), 32+8q+4..7 (sub3)} -> the PV A-frag
// (k = quad*8+j) assembles IN-REGISTER with no cross-lane movement.
// p bits: [p5 p4 p3 p2 p1 p0] = [s5 s2 s4 s3 s1 s0]
__device__ __forceinline__ int kperm(int s) {
    return (s & 0x23) | ((s & 0x18) >> 1) | ((s & 4) << 2);
}

// ---- mask bit-pack: (8,1024,1024) int32 -> (8,1024,16) u64 via wave ballot ----
__global__ __launch_bounds__(256)
void pack_mask_kernel(const int* __restrict__ mask, u64* __restrict__ pm)
{
    const int NW = 8 * T_LEN * (T_LEN / 64);   // 131072 words
    const int lane = threadIdx.x & 63;
    const int gw = (int)((blockIdx.x * blockDim.x + threadIdx.x) >> 6);
    const int nw = (int)((gridDim.x * blockDim.x) >> 6);
    for (int w0 = gw; w0 < NW; w0 += 4 * nw) {
        int v[4];
        #pragma unroll
        for (int i = 0; i < 4; ++i) {
            const int w = w0 + i * nw;
            v[i] = (w < NW) ? mask[(size_t)w * 64 + lane] : 0;
        }
        #pragma unroll
        for (int i = 0; i < 4; ++i) {
            const int w = w0 + i * nw;
            const u64 bb = __ballot(v[i] != 0);
            if (lane == 0 && w < NW) pm[w] = bb;
        }
    }
}

// One block = 8 waves = 512 threads: one (head-batch, 128-row Q tile).
// SWAPPED QK^T: acc = mfma(K, Q) -> C[s][t] with t = l16 lane-local.
// With the kperm'd K tile, P never touches LDS: exp results convert
// straight into the PV A-fragment (was 16 b16 writes + 2 b128 reads +
// lgkm round-trip per wave-iter -> the LDS port was the shared bottleneck).
// Per-lane mask row (1 u64/iter). Double-buffered K/V, 1 barrier/iter,
// pre-scaled Q (0.125*log2e), bias*log2e as MFMA C-init, exp2 softmax,
// ones-MFMA row sums. Epilogue unchanged (O layout identical to r3).
// launch_bounds 2nd arg = workgroups/CU: (512,2) -> 128-VGPR cap
// (est ~90 used; r2's spill tripwire = FETCH_SIZE ballooning).
template<bool PM>
__global__ __launch_bounds__(512, 2)
void qkv_attn_kernel(const float* __restrict__ qkv,
                     const int* __restrict__ mask,
                     const u64* __restrict__ pm,
                     const float* __restrict__ qk_bias,
                     float* __restrict__ out)
{
    // rows of LSTR shorts: Q [128] | K0|V0|K1|V1 [64 each]
    __shared__ __align__(16) char smem[(128 + 4 * 64) * LSTR * 2];  // 49152 B
    short* Qs  = (short*)smem;            // [t][c] swizzled
    short* Ks0 = Qs  + 128 * LSTR;        // [perm(s)][c] swizzled
    short* Vs0 = Ks0 + 64 * LSTR;         // [c][s] swizzled
    short* Ks1 = Vs0 + 64 * LSTR;
    short* Vs1 = Ks1 + 64 * LSTR;
    float* Os  = (float*)smem;            // epilogue reuse: 128 x OSTR fp32

    const int tid  = threadIdx.x;
    const int wave = tid >> 6;
    const int lane = tid & 63;
    const int quad = lane >> 4;
    const int l16  = lane & 15;

    const int bh    = blockIdx.x;   // 0..127: consecutive bh -> XCD round-robin
    const int qtile = blockIdx.y;   // 0..7:  stride-128 ids keep a bh on ONE XCD
    const int b     = bh >> 4;
    const int h     = bh & 15;
    const int t0    = qtile * 128;

    const size_t qbase = ((size_t)b * (3 * NH * CH) + (size_t)h * (3 * CH)) * T_LEN;
    const float* kp = qkv + qbase + (size_t)CH * T_LEN;
    const float* vp = qkv + qbase + (size_t)(2 * CH) * T_LEN;

    const float b_l2e  = qk_bias[0] * 1.44269504088896f;  // exp(x)=exp2(x*log2e)
    const float qscale = 0.125f * 1.44269504088896f;      // folded into Q staging

    // K staging map: 4 s-rows x 2 channels per thread (b32 pair writes)
    const int sg  = tid & 15;          // s-seg: rows sg*4..sg*4+3
    const int c2  = (tid >> 4) * 2;    // channel pair
    const int sp0 = kperm(sg * 4);     // physical base row (sg*4 -> +i contiguous)
    // V staging map: 1 channel x 8 s per thread (b128 write)
    const int c64 = tid >> 3;
    const int sse = (tid & 7) * 8;
    // Q staging map
    const int tse = (tid & 7) * 16;

    const float* kprA = kp + (size_t)c2 * T_LEN + sg * 4;
    const float* kprB = kprA + T_LEN;
    const float* vpr  = vp + (size_t)c64 * T_LEN + sse;

    const int tl = t0 + wave * 16 + l16;   // lane's own t (mask row)
    const u64* pmb = PM ? pm + ((size_t)(h & 7) * T_LEN + tl) * (T_LEN / 64) : nullptr;
    const int* mrow = mask + (size_t)(h & 7) * T_LEN * T_LEN + (size_t)tl * T_LEN;

    // ---- prefetch K/V tile 0 + mask word it=0 ----
    float4 kf0 = *(const float4*)(kprA);
    float4 kf1 = *(const float4*)(kprB);
    float4 vf0 = *(const float4*)(vpr);
    float4 vf1 = *(const float4*)(vpr + 4);
    u64 mn = PM ? pmb[0] : 0ULL;

    // ---- stage Q transposed + swizzled + PRE-SCALED (fp32 -> bf16) ----
    {
        const float* src = qkv + qbase + (size_t)c64 * T_LEN + t0 + tse;
        #pragma unroll
        for (int k = 0; k < 4; ++k) {
            float4 f = *(const float4*)(src + 4 * k);
            const int t = tse + 4 * k;
            Qs[(t + 0) * LSTR + (c64 ^ fsw(t + 0))] = f2bf(f.x * qscale);
            Qs[(t + 1) * LSTR + (c64 ^ fsw(t + 1))] = f2bf(f.y * qscale);
            Qs[(t + 2) * LSTR + (c64 ^ fsw(t + 2))] = f2bf(f.z * qscale);
            Qs[(t + 3) * LSTR + (c64 ^ fsw(t + 3))] = f2bf(f.w * qscale);
        }
    }

    // ---- stage K (perm rows, b32 pairs) / V tile 0 ----
    {
        const float* a = (const float*)&kf0;
        const float* bb = (const float*)&kf1;
        #pragma unroll
        for (int i = 0; i < 4; ++i) {
            const int p = sp0 + i;
            const unsigned w = (unsigned)(unsigned short)f2bf(a[i])
                             | ((unsigned)(unsigned short)f2bf(bb[i]) << 16);
            *(unsigned*)&Ks0[p * LSTR + (c2 ^ fsw(p))] = w;
        }
        const short8 vb = { f2bf(vf0.x), f2bf(vf0.y), f2bf(vf0.z), f2bf(vf0.w),
                            f2bf(vf1.x), f2bf(vf1.y), f2bf(vf1.z), f2bf(vf1.w) };
        *(short8*)&Vs0[c64 * LSTR + (sse ^ fsw(c64))] = vb;
    }
    __syncthreads();

    // ---- loop-invariant Q fragments (B-operand of swapped QK^T) ----
    const int qrow = wave * 16 + l16;
    const short8 aq0 = *(const short8*)&Qs[qrow * LSTR + ((quad * 8)      ^ fsw(qrow))];
    const short8 aq1 = *(const short8*)&Qs[qrow * LSTR + ((quad * 8 + 32) ^ fsw(qrow))];

    const short one_bf = (short)0x3F80;
    const short8 ones8 = (short8){one_bf, one_bf, one_bf, one_bf,
                                  one_bf, one_bf, one_bf, one_bf};

    floatx4 o[4], ol;
    #pragma unroll
    for (int i = 0; i < 4; ++i) o[i] = (floatx4){0.f, 0.f, 0.f, 0.f};
    ol = (floatx4){0.f, 0.f, 0.f, 0.f};

    for (int it = 0; it < 16; ++it) {
        const int s0 = it * 64;
        const short* Kc = (it & 1) ? Ks1 : Ks0;
        const short* Vc = (it & 1) ? Vs1 : Vs0;
        short* Kd = (it & 1) ? Ks0 : Ks1;
        short* Vd = (it & 1) ? Vs0 : Vs1;

        const u64 mcur = mn;
        // issue next-tile K/V global loads + mask word (hidden under compute)
        if (it < 15) {
            kf0 = *(const float4*)(kprA + s0 + 64);
            kf1 = *(const float4*)(kprB + s0 + 64);
            vf0 = *(const float4*)(vpr + s0 + 64);
            vf1 = *(const float4*)(vpr + s0 + 64 + 4);
            if (PM) mn = pmb[it + 1];
        }

        // ---- S^T = K Q (scale/bias pre-folded) -> P = exp2 masked, in-reg ----
        short pa[16];
        #pragma unroll
        for (int sub = 0; sub < 4; ++sub) {
            const int srow = sub * 16 + l16;             // PHYSICAL (perm'd) row
            const int fk   = fsw(srow);
            const short8 bk0 = *(const short8*)&Kc[srow * LSTR + ((quad * 8)      ^ fk)];
            const short8 bk1 = *(const short8*)&Kc[srow * LSTR + ((quad * 8 + 32) ^ fk)];
            floatx4 acc = (floatx4){b_l2e, b_l2e, b_l2e, b_l2e};
            acc = __builtin_amdgcn_mfma_f32_16x16x32_bf16(bk0, aq0, acc, 0, 0, 0);
            acc = __builtin_amdgcn_mfma_f32_16x16x32_bf16(bk1, aq1, acc, 0, 0, 0);
            // original s for (sub, quad, r): 32*(sub>>1) + 8*quad + 4*(sub&1) + r
            const int sbase = 32 * (sub >> 1) + 4 * (sub & 1) + 8 * quad;
            unsigned mseg = 0;
            if (PM) mseg = (unsigned)(mcur >> sbase) & 0xFu;
            #pragma unroll
            for (int r = 0; r < 4; ++r) {
                bool keep;
                if (PM) keep = ((mseg >> r) & 1u) != 0;
                else    keep = mrow[s0 + sbase + r] != 0;
                const float e = __builtin_amdgcn_exp2f(acc[r]);
                pa[sub * 4 + r] = f2bf(keep ? e : 0.f);
            }
        }
        // PV A-frags directly from registers (kperm made the order line up):
        // pa[0..7]  = s  0..31 slice (k = quad*8 + j)
        // pa[8..15] = s 32..63 slice
        const short8 ap0 = *(const short8*)&pa[0];
        const short8 ap1 = *(const short8*)&pa[8];

        // ---- O += P V ; l += P . 1 ----
        __builtin_amdgcn_s_setprio(1);
        #pragma unroll
        for (int csub = 0; csub < 4; ++csub) {
            const int vrow = csub * 16 + l16;
            const int fv   = fsw(vrow);
            const short8 bv0 = *(const short8*)&Vc[vrow * LSTR + ((quad * 8)      ^ fv)];
            const short8 bv1 = *(const short8*)&Vc[vrow * LSTR + ((quad * 8 + 32) ^ fv)];
            o[csub] = __builtin_amdgcn_mfma_f32_16x16x32_bf16(ap0, bv0, o[csub], 0, 0, 0);
            o[csub] = __builtin_amdgcn_mfma_f32_16x16x32_bf16(ap1, bv1, o[csub], 0, 0, 0);
        }
        ol = __builtin_amdgcn_mfma_f32_16x16x32_bf16(ap0, ones8, ol, 0, 0, 0);
        ol = __builtin_amdgcn_mfma_f32_16x16x32_bf16(ap1, ones8, ol, 0, 0, 0);
        __builtin_amdgcn_s_setprio(0);

        // ---- write prefetched next tile into the other buffer; single barrier ----
        if (it < 15) {
            const float* a = (const float*)&kf0;
            const float* bb = (const float*)&kf1;
            unsigned kw[4];
            #pragma unroll
            for (int i = 0; i < 4; ++i)
                kw[i] = (unsigned)(unsigned short)f2bf(a[i])
                      | ((unsigned)(unsigned short)f2bf(bb[i]) << 16);
            const short8 vb = { f2bf(vf0.x), f2bf(vf0.y), f2bf(vf0.z), f2bf(vf0.w),
                                f2bf(vf1.x), f2bf(vf1.y), f2bf(vf1.z), f2bf(vf1.w) };
            #pragma unroll
            for (int i = 0; i < 4; ++i) {
                const int p = sp0 + i;
                *(unsigned*)&Kd[p * LSTR + (c2 ^ fsw(p))] = kw[i];
            }
            *(short8*)&Vd[c64 * LSTR + (sse ^ fsw(c64))] = vb;
            __syncthreads();
        }
    }

    // ---- epilogue: normalize, restage fp32 via LDS for coalesced [c][t] stores ----
    __syncthreads();   // all compute done before Os overwrites Qs/K0/V0
    float inv[4];
    #pragma unroll
    for (int r = 0; r < 4; ++r) inv[r] = (ol[r] > 0.f) ? 1.f / ol[r] : 0.f;
    const int osw = wave << 3;                     // == ((t>>4)<<3), t>>4 = wave
    #pragma unroll
    for (int csub = 0; csub < 4; ++csub)
        #pragma unroll
        for (int r = 0; r < 4; ++r)
            Os[(wave * 16 + quad * 4 + r) * OSTR + ((csub * 16 + l16) ^ osw)] =
                o[csub][r] * inv[r];
    __syncthreads();
    {
        const int g  = (tid & 7) << 3;             // == ((t>>4)<<3), t>>4 = tid&7
        const int cg = c64 ^ g;
        float* dst = out + ((size_t)b * (NH * CH) + (size_t)h * CH + c64) * T_LEN + t0 + tse;
        #pragma unroll
        for (int k = 0; k < 4; ++k) {
            const int t = tse + 4 * k;
            float4 f;
            f.x = Os[(t + 0) * OSTR + cg];
            f.y = Os[(t + 1) * OSTR + cg];
            f.z = Os[(t + 2) * OSTR + cg];
            f.w = Os[(t + 3) * OSTR + cg];
            *(float4*)(dst + 4 * k) = f;
        }
    }
}

extern "C" void kernel_launch(void* const* d_in, const int* in_sizes, int n_in,
                              void* d_out, int out_size, void* d_ws, size_t ws_size,
                              hipStream_t stream) {
    const float* qkv     = (const float*)d_in[0];
    const int*   mask    = (const int*)d_in[1];
    const float* qk_bias = (const float*)d_in[2];
    float*       out     = (float*)d_out;

    const size_t pm_bytes = (size_t)8 * T_LEN * (T_LEN / 64) * sizeof(u64);  // 1 MiB
    u64* pm = nullptr;
    if (d_ws && ws_size >= pm_bytes) {
        pm = (u64*)d_ws;
        pack_mask_kernel<<<2048, 256, 0, stream>>>(mask, pm);
    }

    dim3 grid(8 * NH, T_LEN / 128);  // (head-batches, q-tiles) = (128, 8)
    if (pm) qkv_attn_kernel<true ><<<grid, 512, 0, stream>>>(qkv, mask, pm, qk_bias, out);
    else    qkv_attn_kernel<false><<<grid, 512, 0, stream>>>(qkv, mask, nullptr, qk_bias, out);
}

// Round 7
// 232.508 us; speedup vs baseline: 1.4319x; 1.0409x over previous
//
#include <hip/hip_runtime.h>
#include <hip/hip_bf16.h>

#define T_LEN 1024
#define NH    16
#define CH    64
#define LSTR  64        // LDS bf16 row stride in shorts: 128 B, swizzled (no pad)

typedef __attribute__((ext_vector_type(8))) short short8;
typedef __attribute__((ext_vector_type(4))) float floatx4;
typedef unsigned long long u64;

__device__ __forceinline__ short f2bf(float x) {
    __hip_bfloat16 b = __float2bfloat16(x);   // RNE (prologue-only scalar path)
    return *(short*)&b;
}
// HW packed conversion: dst.lo16 = bf16(lo), dst.hi16 = bf16(hi). 1 inst vs
// ~5/elem for the __float2bfloat16 bit-twiddle — the main VALU sink at
// 32 cvts/thread/iter (r6: VALUBusy 42% dominated by staging+P cvt).
__device__ __forceinline__ unsigned cvt_pk_bf16(float lo, float hi) {
    unsigned r;
    asm("v_cvt_pk_bf16_f32 %0, %1, %2" : "=v"(r) : "v"(lo), "v"(hi));
    return r;
}
// XOR block-swizzle for stride-64-short (128 B) rows.
__device__ __forceinline__ int fsw(int row) {
    return (((row & 7) ^ ((row >> 3) & 7)) << 3);
}
// K-row permutation: after the 4 sub-tile swapped-QK^T MFMAs, lane (q,l16)
// holds exactly the s-values of its PV A-fragment slot -> P assembles
// in-register (zero LDS, zero cross-lane). p = [s5 s2 s4 s3 s1 s0].
__device__ __forceinline__ int kperm(int s) {
    return (s & 0x23) | ((s & 0x18) >> 1) | ((s & 4) << 2);
}

// ---- mask bit-pack: (8,1024,1024) int32 -> (8,1024,16) u64 via wave ballot ----
__global__ __launch_bounds__(256)
void pack_mask_kernel(const int* __restrict__ mask, u64* __restrict__ pm)
{
    const int NW = 8 * T_LEN * (T_LEN / 64);   // 131072 words
    const int lane = threadIdx.x & 63;
    const int gw = (int)((blockIdx.x * blockDim.x + threadIdx.x) >> 6);
    const int nw = (int)((gridDim.x * blockDim.x) >> 6);
    for (int w0 = gw; w0 < NW; w0 += 4 * nw) {
        int v[4];
        #pragma unroll
        for (int i = 0; i < 4; ++i) {
            const int w = w0 + i * nw;
            v[i] = (w < NW) ? mask[(size_t)w * 64 + lane] : 0;
        }
        #pragma unroll
        for (int i = 0; i < 4; ++i) {
            const int w = w0 + i * nw;
            const u64 bb = __ballot(v[i] != 0);
            if (lane == 0 && w < NW) pm[w] = bb;
        }
    }
}

// One block = 8 waves = 512 threads: one (head-batch, 128-row Q tile).
// r6 structure (swapped QK^T, kperm'd K, P in-register, dbuf K/V, 1
// barrier/iter) + two changes:
//  (1) all bulk fp32->bf16 via v_cvt_pk_bf16_f32 (VALU was the top sink);
//  (2) 32 KB LDS: Q rows are dead after the one-time frag load, so buffer A
//      overlays them (tile 0 staged into buffer B -> no extra barrier).
//      Grid 1024 = exactly 4 resident blocks/CU (LDS allows 5, VGPR@64 -> 4).
// launch_bounds 2nd arg = workgroups/CU: (512,2) -> 128-VGPR cap; r6's
// demand was 64. Spill tripwire: FETCH_SIZE ballooning (r2).
template<bool PM>
__global__ __launch_bounds__(512, 2)
void qkv_attn_kernel(const float* __restrict__ qkv,
                     const int* __restrict__ mask,
                     const u64* __restrict__ pm,
                     const float* __restrict__ qk_bias,
                     float* __restrict__ out)
{
    // 256 rows of LSTR shorts = 32768 B.
    // prologue: rows 0..127 = Q [t][c]; rows 128..255 = K0|V0 (buffer B).
    // steady:   A = rows 0..127 (K|V), B = rows 128..255 (K|V).
    // epilogue: whole 32 KB = Os fp32 [128][64] double-XOR swizzled.
    __shared__ __align__(16) char smem[256 * LSTR * 2];
    short* Qs = (short*)smem;
    short* KA = Qs;                      // rows   0.. 63
    short* VA = Qs + 64 * LSTR;          // rows  64..127
    short* KB = Qs + 128 * LSTR;         // rows 128..191
    short* VB = Qs + 192 * LSTR;         // rows 192..255
    float* Os = (float*)smem;

    const int tid  = threadIdx.x;
    const int wave = tid >> 6;
    const int lane = tid & 63;
    const int quad = lane >> 4;
    const int l16  = lane & 15;

    const int bh    = blockIdx.x;   // 0..127: consecutive bh -> XCD round-robin
    const int qtile = blockIdx.y;   // 0..7:  stride-128 ids keep a bh on ONE XCD
    const int b     = bh >> 4;
    const int h     = bh & 15;
    const int t0    = qtile * 128;

    const size_t qbase = ((size_t)b * (3 * NH * CH) + (size_t)h * (3 * CH)) * T_LEN;
    const float* kp = qkv + qbase + (size_t)CH * T_LEN;
    const float* vp = qkv + qbase + (size_t)(2 * CH) * T_LEN;

    const float b_l2e  = qk_bias[0] * 1.44269504088896f;  // exp(x)=exp2(x*log2e)
    const float qscale = 0.125f * 1.44269504088896f;      // folded into Q staging

    // K staging map: 4 s-rows x 2 channels per thread (b32 pair = cvt_pk word)
    const int sg  = tid & 15;          // s-group: rows sg*4..sg*4+3
    const int c2  = (tid >> 4) * 2;    // channel pair
    const int sp0 = kperm(sg * 4);     // physical base row (contiguous for +i<4)
    // V staging map: 1 channel x 8 s per thread (b128 write)
    const int c64 = tid >> 3;
    const int sse = (tid & 7) * 8;
    // Q staging map
    const int tse = (tid & 7) * 16;

    const float* kprA = kp + (size_t)c2 * T_LEN + sg * 4;
    const float* kprB = kprA + T_LEN;
    const float* vpr  = vp + (size_t)c64 * T_LEN + sse;

    const int tl = t0 + wave * 16 + l16;   // lane's own t (mask row)
    const u64* pmb = PM ? pm + ((size_t)(h & 7) * T_LEN + tl) * (T_LEN / 64) : nullptr;
    const int* mrow = mask + (size_t)(h & 7) * T_LEN * T_LEN + (size_t)tl * T_LEN;

    // ---- prefetch K/V tile 0 + mask word it=0 ----
    float4 kf0 = *(const float4*)(kprA);
    float4 kf1 = *(const float4*)(kprB);
    float4 vf0 = *(const float4*)(vpr);
    float4 vf1 = *(const float4*)(vpr + 4);
    u64 mn = PM ? pmb[0] : 0ULL;

    // ---- stage Q transposed + swizzled + PRE-SCALED (rows 0..127) ----
    {
        const float* src = qkv + qbase + (size_t)c64 * T_LEN + t0 + tse;
        #pragma unroll
        for (int k = 0; k < 4; ++k) {
            float4 f = *(const float4*)(src + 4 * k);
            const int t = tse + 4 * k;
            Qs[(t + 0) * LSTR + (c64 ^ fsw(t + 0))] = f2bf(f.x * qscale);
            Qs[(t + 1) * LSTR + (c64 ^ fsw(t + 1))] = f2bf(f.y * qscale);
            Qs[(t + 2) * LSTR + (c64 ^ fsw(t + 2))] = f2bf(f.z * qscale);
            Qs[(t + 3) * LSTR + (c64 ^ fsw(t + 3))] = f2bf(f.w * qscale);
        }
    }
    __syncthreads();

    // ---- loop-invariant Q fragments (B-operand of swapped QK^T) ----
    const int qrow = wave * 16 + l16;
    const short8 aq0 = *(const short8*)&Qs[qrow * LSTR + ((quad * 8)      ^ fsw(qrow))];
    const short8 aq1 = *(const short8*)&Qs[qrow * LSTR + ((quad * 8 + 32) ^ fsw(qrow))];

    // ---- stage K/V tile 0 into buffer B (doesn't touch Q rows -> no barrier) ----
    {
        const float* a  = (const float*)&kf0;
        const float* bb = (const float*)&kf1;
        #pragma unroll
        for (int i = 0; i < 4; ++i) {
            const int p = sp0 + i;
            *(unsigned*)&KB[p * LSTR + (c2 ^ fsw(p))] = cvt_pk_bf16(a[i], bb[i]);
        }
        uint4 vw;
        vw.x = cvt_pk_bf16(vf0.x, vf0.y);
        vw.y = cvt_pk_bf16(vf0.z, vf0.w);
        vw.z = cvt_pk_bf16(vf1.x, vf1.y);
        vw.w = cvt_pk_bf16(vf1.z, vf1.w);
        *(uint4*)&VB[c64 * LSTR + (sse ^ fsw(c64))] = vw;
    }
    __syncthreads();

    const short one_bf = (short)0x3F80;
    const short8 ones8 = (short8){one_bf, one_bf, one_bf, one_bf,
                                  one_bf, one_bf, one_bf, one_bf};

    floatx4 o[4], ol;
    #pragma unroll
    for (int i = 0; i < 4; ++i) o[i] = (floatx4){0.f, 0.f, 0.f, 0.f};
    ol = (floatx4){0.f, 0.f, 0.f, 0.f};

    for (int it = 0; it < 16; ++it) {
        const int s0 = it * 64;
        // even it -> compute from B (tile0 staged there), stage next into A
        const short* Kc = (it & 1) ? KA : KB;
        const short* Vc = (it & 1) ? VA : VB;
        short* Kd = (it & 1) ? KB : KA;
        short* Vd = (it & 1) ? VB : VA;

        const u64 mcur = mn;
        // issue next-tile K/V global loads + mask word (hidden under compute)
        if (it < 15) {
            kf0 = *(const float4*)(kprA + s0 + 64);
            kf1 = *(const float4*)(kprB + s0 + 64);
            vf0 = *(const float4*)(vpr + s0 + 64);
            vf1 = *(const float4*)(vpr + s0 + 64 + 4);
            if (PM) mn = pmb[it + 1];
        }

        // ---- S^T = K Q (scale/bias pre-folded) -> P = exp2 masked, in-reg ----
        unsigned pa32[8];
        #pragma unroll
        for (int sub = 0; sub < 4; ++sub) {
            const int srow = sub * 16 + l16;             // PHYSICAL (perm'd) row
            const int fk   = fsw(srow);
            const short8 bk0 = *(const short8*)&Kc[srow * LSTR + ((quad * 8)      ^ fk)];
            const short8 bk1 = *(const short8*)&Kc[srow * LSTR + ((quad * 8 + 32) ^ fk)];
            floatx4 acc = (floatx4){b_l2e, b_l2e, b_l2e, b_l2e};
            acc = __builtin_amdgcn_mfma_f32_16x16x32_bf16(bk0, aq0, acc, 0, 0, 0);
            acc = __builtin_amdgcn_mfma_f32_16x16x32_bf16(bk1, aq1, acc, 0, 0, 0);
            // original s for (sub, quad, r): 32*(sub>>1) + 8*quad + 4*(sub&1) + r
            const int sbase = 32 * (sub >> 1) + 4 * (sub & 1) + 8 * quad;
            unsigned mseg = 0;
            if (PM) mseg = (unsigned)(mcur >> sbase) & 0xFu;
            float f[4];
            #pragma unroll
            for (int r = 0; r < 4; ++r) {
                bool keep;
                if (PM) keep = ((mseg >> r) & 1u) != 0;
                else    keep = mrow[s0 + sbase + r] != 0;
                const float e = __builtin_amdgcn_exp2f(acc[r]);
                f[r] = keep ? e : 0.f;
            }
            pa32[sub * 2 + 0] = cvt_pk_bf16(f[0], f[1]);
            pa32[sub * 2 + 1] = cvt_pk_bf16(f[2], f[3]);
        }
        // PV A-frags directly from registers (kperm made the order line up)
        const short8 ap0 = *(const short8*)&pa32[0];   // s  0..31 slice
        const short8 ap1 = *(const short8*)&pa32[4];   // s 32..63 slice

        // ---- O += P V ; l += P . 1 ----
        __builtin_amdgcn_s_setprio(1);
        #pragma unroll
        for (int csub = 0; csub < 4; ++csub) {
            const int vrow = csub * 16 + l16;
            const int fv   = fsw(vrow);
            const short8 bv0 = *(const short8*)&Vc[vrow * LSTR + ((quad * 8)      ^ fv)];
            const short8 bv1 = *(const short8*)&Vc[vrow * LSTR + ((quad * 8 + 32) ^ fv)];
            o[csub] = __builtin_amdgcn_mfma_f32_16x16x32_bf16(ap0, bv0, o[csub], 0, 0, 0);
            o[csub] = __builtin_amdgcn_mfma_f32_16x16x32_bf16(ap1, bv1, o[csub], 0, 0, 0);
        }
        ol = __builtin_amdgcn_mfma_f32_16x16x32_bf16(ap0, ones8, ol, 0, 0, 0);
        ol = __builtin_amdgcn_mfma_f32_16x16x32_bf16(ap1, ones8, ol, 0, 0, 0);
        __builtin_amdgcn_s_setprio(0);

        // ---- write prefetched next tile into the other buffer; single barrier ----
        if (it < 15) {
            const float* a  = (const float*)&kf0;
            const float* bb = (const float*)&kf1;
            unsigned kw[4];
            #pragma unroll
            for (int i = 0; i < 4; ++i) kw[i] = cvt_pk_bf16(a[i], bb[i]);
            uint4 vw;
            vw.x = cvt_pk_bf16(vf0.x, vf0.y);
            vw.y = cvt_pk_bf16(vf0.z, vf0.w);
            vw.z = cvt_pk_bf16(vf1.x, vf1.y);
            vw.w = cvt_pk_bf16(vf1.z, vf1.w);
            #pragma unroll
            for (int i = 0; i < 4; ++i) {
                const int p = sp0 + i;
                *(unsigned*)&Kd[p * LSTR + (c2 ^ fsw(p))] = kw[i];
            }
            *(uint4*)&Vd[c64 * LSTR + (sse ^ fsw(c64))] = vw;
            __syncthreads();
        }
    }

    // ---- epilogue: Os fp32 [128][64] fills the whole 32 KB; double-XOR
    //      swizzle (col ^ (wave<<3) ^ (quad<<4)) -> max 2-way on both sides ----
    __syncthreads();   // all compute done before Os overwrites K/V buffers
    float inv[4];
    #pragma unroll
    for (int r = 0; r < 4; ++r) inv[r] = (ol[r] > 0.f) ? 1.f / ol[r] : 0.f;
    const int okeyw = (wave << 3) ^ (quad << 4);
    #pragma unroll
    for (int csub = 0; csub < 4; ++csub)
        #pragma unroll
        for (int r = 0; r < 4; ++r)
            Os[(wave * 16 + quad * 4 + r) * 64 + ((csub * 16 + l16) ^ okeyw)] =
                o[csub][r] * inv[r];
    __syncthreads();
    {
        float* dst = out + ((size_t)b * (NH * CH) + (size_t)h * CH + c64) * T_LEN
                   + t0 + tse;
        #pragma unroll
        for (int k = 0; k < 4; ++k) {
            float4 f;
            #pragma unroll
            for (int j = 0; j < 4; ++j) {
                const int rl = tse + 4 * k + j;
                const int ok = ((rl >> 4) << 3) ^ (((rl >> 2) & 3) << 4);
                ((float*)&f)[j] = Os[rl * 64 + (c64 ^ ok)];
            }
            *(float4*)(dst + 4 * k) = f;
        }
    }
}

extern "C" void kernel_launch(void* const* d_in, const int* in_sizes, int n_in,
                              void* d_out, int out_size, void* d_ws, size_t ws_size,
                              hipStream_t stream) {
    const float* qkv     = (const float*)d_in[0];
    const int*   mask    = (const int*)d_in[1];
    const float* qk_bias = (const float*)d_in[2];
    float*       out     = (float*)d_out;

    const size_t pm_bytes = (size_t)8 * T_LEN * (T_LEN / 64) * sizeof(u64);  // 1 MiB
    u64* pm = nullptr;
    if (d_ws && ws_size >= pm_bytes) {
        pm = (u64*)d_ws;
        pack_mask_kernel<<<2048, 256, 0, stream>>>(mask, pm);
    }

    dim3 grid(8 * NH, T_LEN / 128);  // (head-batches, q-tiles) = (128, 8)
    if (pm) qkv_attn_kernel<true ><<<grid, 512, 0, stream>>>(qkv, mask, pm, qk_bias, out);
    else    qkv_attn_kernel<false><<<grid, 512, 0, stream>>>(qkv, mask, nullptr, qk_bias, out);
}